// Round 9
// baseline (1680.266 us; speedup 1.0000x reference)
//
#include <hip/hip_runtime.h>
#include <math.h>

// PnPNystra attention, MFMA v7: 2-blocks/CU k_main.
// 5 LDS plane-pairs (81920 B exactly), KM/KV stashed to og during pinv,
// kv1/den in dead plane regions (no atomics), q read direct from global in F,
// __launch_bounds__(1024,8) -> VGPR<=64 -> 32 waves/CU.
// Numerics unchanged from v5: split f16 (v ~= h + l/2048), 3x mfma_f32_16x16x32_f16,
// Z scaled by 1024. G=4096 groups, N=256, d=64, L=64.

#define G_TOT 4096
#define TPB_R 256
#define TPB_M 1024
typedef _Float16 f16;
typedef __attribute__((ext_vector_type(2))) _Float16 f16x2;
typedef __attribute__((ext_vector_type(4))) _Float16 f16x4;
typedef __attribute__((ext_vector_type(8))) _Float16 f16x8;
typedef __attribute__((ext_vector_type(4))) float f32x4;
typedef __attribute__((ext_vector_type(16))) float f32x16;

#define NPLANES 10
#define SMEM_BYTES (NPLANES * 4096 * 2)  // 81920 B -> 2 blocks/CU

#define LSCALE 2048.0f
#define LINV   (1.0f / 2048.0f)
#define ZS     1024.0f
#define ZINV   (1.0f / 1024.0f)

struct HL { f16 h, l; };
__device__ __forceinline__ HL split2(float v) {
    HL r;
    r.h = (f16)v;
    r.l = (f16)((v - (float)r.h) * LSCALE);
    return r;
}
__device__ __forceinline__ float join2(f16 h, f16 l) {
    return (float)h + (float)l * LINV;
}
__device__ __forceinline__ int swi(int r, int c) {
    return (r << 6) + (c ^ ((r & 7) << 3));
}
__device__ __forceinline__ float activ_f(float x) {
    return __expf(fminf(x, 5.0f)) + fmaxf(x - 5.0f, 0.0f);
}
__device__ __forceinline__ float activ_r(float x) {
    return expf(fminf(x, 5.0f)) + fmaxf(x - 5.0f, 0.0f);
}
__device__ __forceinline__ void split_w(f16* Ph, f16* Pl, int r, int c, float v) {
    HL s = split2(v);
    const int o = swi(r, c);
    Ph[o] = s.h;
    Pl[o] = s.l;
}
__device__ __forceinline__ f16x2 mk2(f16 a, f16 b) { f16x2 r; r[0]=a; r[1]=b; return r; }
__device__ __forceinline__ f16x4 mk4(f16 a, f16 b, f16 c, f16 d) { f16x4 r; r[0]=a;r[1]=b;r[2]=c;r[3]=d; return r; }
__device__ __forceinline__ f32x4 z4() { f32x4 z = {0.f,0.f,0.f,0.f}; return z; }
__device__ __forceinline__ f32x16 z16() {
    f32x16 z;
#pragma unroll
    for (int i = 0; i < 16; ++i) z[i] = 0.f;
    return z;
}

struct Frag { f16x8 h[2], l[2]; };

__device__ __forceinline__ Frag ld_frag(const f16* __restrict__ Ph,
                                        const f16* __restrict__ Pl,
                                        int row, int kg) {
    Frag f;
    const int base = row << 6, x = (row & 7) << 3;
#pragma unroll
    for (int s = 0; s < 2; ++s) {
        const int o = base + ((((s << 5) + (kg << 3))) ^ x);
        f.h[s] = *(const f16x8*)(Ph + o);
        f.l[s] = *(const f16x8*)(Pl + o);
    }
    return f;
}

// A-frag built straight from a global f32 row (no LDS staging)
__device__ __forceinline__ Frag mk_gfrag(const float* __restrict__ row, int kg) {
    Frag f;
#pragma unroll
    for (int s = 0; s < 2; ++s) {
        const float* p = row + (s << 5) + (kg << 3);
        float4 a = *(const float4*)p;
        float4 b = *(const float4*)(p + 4);
        float vv0 = a.x, vv1 = a.y, vv2 = a.z, vv3 = a.w;
        float vv4 = b.x, vv5 = b.y, vv6 = b.z, vv7 = b.w;
        HL s0 = split2(vv0), s1 = split2(vv1), s2 = split2(vv2), s3 = split2(vv3);
        HL s4 = split2(vv4), s5 = split2(vv5), s6 = split2(vv6), s7 = split2(vv7);
        f16x8 h, l;
        h[0]=s0.h; h[1]=s1.h; h[2]=s2.h; h[3]=s3.h; h[4]=s4.h; h[5]=s5.h; h[6]=s6.h; h[7]=s7.h;
        l[0]=s0.l; l[1]=s1.l; l[2]=s2.l; l[3]=s3.l; l[4]=s4.l; l[5]=s5.l; l[6]=s6.l; l[7]=s7.l;
        f.h[s] = h; f.l[s] = l;
    }
    return f;
}

__device__ __forceinline__ f32x4 mm16_rr(const Frag& A, const Frag& B, f32x4 acc) {
    f32x4 ax1 = z4(), ax2 = z4();
#pragma unroll
    for (int s = 0; s < 2; ++s) {
        acc = __builtin_amdgcn_mfma_f32_16x16x32_f16(A.h[s], B.h[s], acc, 0, 0, 0);
        ax1 = __builtin_amdgcn_mfma_f32_16x16x32_f16(A.h[s], B.l[s], ax1, 0, 0, 0);
        ax2 = __builtin_amdgcn_mfma_f32_16x16x32_f16(A.l[s], B.h[s], ax2, 0, 0, 0);
    }
    acc += (ax1 + ax2) * LINV;
    return acc;
}

__device__ __forceinline__ void wfrag_rm(f16* Ph, f16* Pl, int Rb, int C, const float* v) {
#pragma unroll
    for (int m = 0; m < 4; ++m) split_w(Ph, Pl, Rb + m, C, v[m]);
}
__device__ __forceinline__ void wfrag_t(f16* Ph, f16* Pl, int Rb, int C, const float* v) {
    const int o = swi(C, Rb);
    HL s0 = split2(v[0]), s1 = split2(v[1]), s2 = split2(v[2]), s3 = split2(v[3]);
    *(f16x4*)(Ph + o) = mk4(s0.h, s1.h, s2.h, s3.h);
    *(f16x4*)(Pl + o) = mk4(s0.l, s1.l, s2.l, s3.l);
}

// ---- staging helpers (1024 threads) ----
__device__ __forceinline__ void wr_rm(float4 vv, f16* Ph, f16* Pl, int t) {
    const int r = t >> 4, c4 = (t & 15) << 2;
    const int o = swi(r, c4);
    HL s0 = split2(vv.x), s1 = split2(vv.y), s2 = split2(vv.z), s3 = split2(vv.w);
    *(f16x4*)(Ph + o) = mk4(s0.h, s1.h, s2.h, s3.h);
    *(f16x4*)(Pl + o) = mk4(s0.l, s1.l, s2.l, s3.l);
}
__device__ __forceinline__ void ld_vt(const float* __restrict__ src, int t,
                                      float2& va, float2& vb) {
    const int n0 = (t >> 5) << 1, e0 = (t & 31) << 1;
    va = *(const float2*)(src + (size_t)n0 * 64 + e0);
    vb = *(const float2*)(src + (size_t)(n0 + 1) * 64 + e0);
}
__device__ __forceinline__ void wr_vt(float2 va, float2 vb, f16* Ph, f16* Pl, int t) {
    const int n0 = (t >> 5) << 1, e0 = (t & 31) << 1;
    HL ax = split2(va.x), ay = split2(va.y), bx = split2(vb.x), by = split2(vb.y);
    const int o0 = swi(e0, n0), o1 = swi(e0 + 1, n0);
    *(f16x2*)(Ph + o0) = mk2(ax.h, bx.h);
    *(f16x2*)(Pl + o0) = mk2(ax.l, bx.l);
    *(f16x2*)(Ph + o1) = mk2(ay.h, by.h);
    *(f16x2*)(Pl + o1) = mk2(ay.l, by.l);
}
__device__ __forceinline__ void pool_global1024(const float* __restrict__ src,
                                                f16* Ph, f16* Pl, int t) {
    const int L = t >> 4, d0 = (t & 15) << 2;
    const int nb = ((L >> 3) << 5) + ((L & 7) << 1);
    const float* p = src + (size_t)nb * 64 + d0;
    float4 a = *(const float4*)p;
    float4 b = *(const float4*)(p + 64);
    float4 c = *(const float4*)(p + 1024);
    float4 d = *(const float4*)(p + 1088);
    HL s0 = split2(0.25f * (a.x + b.x + c.x + d.x));
    HL s1 = split2(0.25f * (a.y + b.y + c.y + d.y));
    HL s2 = split2(0.25f * (a.z + b.z + c.z + d.z));
    HL s3 = split2(0.25f * (a.w + b.w + c.w + d.w));
    const int o = swi(L, d0);
    *(f16x4*)(Ph + o) = mk4(s0.h, s1.h, s2.h, s3.h);
    *(f16x4*)(Pl + o) = mk4(s0.l, s1.l, s2.l, s3.l);
}
__device__ __forceinline__ void pool_lds512(const f16* Kh, const f16* Kl,
                                            f16* Ph, f16* Pl, int t, int tt) {
    const int ll = t >> 5, d0 = (t & 31) << 1;
    const int rb = ((ll >> 3) << 5) + ((ll & 7) << 1);
    float s0 = 0.f, s1 = 0.f;
#pragma unroll
    for (int rr = 0; rr < 4; ++rr) {
        const int r = rb + (rr & 1) + ((rr >> 1) << 4);
        const int o = swi(r, d0);
        f16x2 h = *(const f16x2*)(Kh + o);
        f16x2 l = *(const f16x2*)(Kl + o);
        s0 += join2(h[0], l[0]);
        s1 += join2(h[1], l[1]);
    }
    const int L = (tt << 4) + ll;
    HL p0 = split2(0.25f * s0), p1 = split2(0.25f * s1);
    const int o = swi(L, d0);
    *(f16x2*)(Ph + o) = mk2(p0.h, p1.h);
    *(f16x2*)(Pl + o) = mk2(p0.l, p1.l);
}

// ---- k_reduce helpers (unchanged) ----
__device__ __forceinline__ f32x16 mm64q(const f16* __restrict__ Ah, const f16* __restrict__ Al,
                                        const f16* __restrict__ Bh, const f16* __restrict__ Bl,
                                        int lane, int wr, int wc, f32x16 acc) {
    const int cl = lane & 31, hh = lane >> 5;
    const int ar = (wr << 5) + cl, br = (wc << 5) + cl;
    const int abase = ar << 6, axor = (ar & 7) << 3;
    const int bbase = br << 6, bxor = (br & 7) << 3;
    f32x16 ax1 = z16();
    f32x16 ax2 = z16();
#pragma unroll
    for (int ks = 0; ks < 4; ++ks) {
        const int k0 = (ks << 4) + (hh << 3);
        const int ao = abase + (k0 ^ axor);
        const int bo = bbase + (k0 ^ bxor);
        f16x8 a_h = *(const f16x8*)(Ah + ao);
        f16x8 a_l = *(const f16x8*)(Al + ao);
        f16x8 b_h = *(const f16x8*)(Bh + bo);
        f16x8 b_l = *(const f16x8*)(Bl + bo);
        acc = __builtin_amdgcn_mfma_f32_32x32x16_f16(a_h, b_h, acc, 0, 0, 0);
        ax1 = __builtin_amdgcn_mfma_f32_32x32x16_f16(a_h, b_l, ax1, 0, 0, 0);
        ax2 = __builtin_amdgcn_mfma_f32_32x32x16_f16(a_l, b_h, ax2, 0, 0, 0);
    }
    acc += (ax1 + ax2) * LINV;
    return acc;
}
__device__ __forceinline__ void pool_global_r(const float* __restrict__ src,
                                              f16* Ph, f16* Pl, int t) {
    const int ll = t >> 4, d0 = (t & 15) << 2;
    const int rb = ((ll >> 3) << 5) + ((ll & 7) << 1);
#pragma unroll
    for (int tt = 0; tt < 4; ++tt) {
        const float* p = src + (size_t)((tt << 6) + rb) * 64 + d0;
        float4 a = *(const float4*)p;
        float4 b = *(const float4*)(p + 64);
        float4 c = *(const float4*)(p + 1024);
        float4 d = *(const float4*)(p + 1088);
        const int L = (tt << 4) + ll;
        split_w(Ph, Pl, L, d0 + 0, 0.25f * (a.x + b.x + c.x + d.x));
        split_w(Ph, Pl, L, d0 + 1, 0.25f * (a.y + b.y + c.y + d.y));
        split_w(Ph, Pl, L, d0 + 2, 0.25f * (a.z + b.z + c.z + d.z));
        split_w(Ph, Pl, L, d0 + 3, 0.25f * (a.w + b.w + c.w + d.w));
    }
}

#define WAVE_SUM32(v)            \
    v += __shfl_xor(v, 1);       \
    v += __shfl_xor(v, 2);       \
    v += __shfl_xor(v, 4);       \
    v += __shfl_xor(v, 8);       \
    v += __shfl_xor(v, 16);

__global__ void k_init(float* ws) {
    if (threadIdx.x < 2) ws[threadIdx.x] = 0.0f;
}

__global__ __launch_bounds__(TPB_R) void k_reduce(const float* __restrict__ q,
                                                  const float* __restrict__ k,
                                                  float* __restrict__ ws) {
    __shared__ f16 pls[4 * 4096];
    __shared__ float rowS[64], colS[64];
    const int t = threadIdx.x, g = blockIdx.x;
    const int lane = t & 63, wv = t >> 6, wr = wv >> 1, wc = wv & 1;
    const int cl = lane & 31, hh = lane >> 5;
    if (t < 64) rowS[t] = 0.f;
    else if (t < 128) colS[t - 64] = 0.f;
    pool_global_r(q + (size_t)g * 16384, pls, pls + 4096, t);
    pool_global_r(k + (size_t)g * 16384, pls + 8192, pls + 12288, t);
    __syncthreads();
    f32x16 a = mm64q(pls, pls + 4096, pls + 8192, pls + 12288, lane, wr, wc, z16());
    float colp = 0.f;
#pragma unroll
    for (int m = 0; m < 16; ++m) {
        float x = activ_r(a[m]);
        const int R = (wr << 5) + (m & 3) + ((m >> 2) << 3) + (hh << 2);
        float vs = x;
        WAVE_SUM32(vs)
        if (cl == 0) atomicAdd(&rowS[R], vs);
        colp += x;
    }
    colp += __shfl_xor(colp, 32);
    if (hh == 0) atomicAdd(&colS[(wc << 5) + cl], colp);
    __syncthreads();
    if (t < 64) {
        float vmx = rowS[t];
        for (int off = 1; off < 64; off <<= 1) vmx = fmaxf(vmx, __shfl_xor(vmx, off));
        if (t == 0) atomicMax((int*)ws, __float_as_int(vmx));
    } else if (t < 128) {
        float vmx = colS[t - 64];
        for (int off = 1; off < 64; off <<= 1) vmx = fmaxf(vmx, __shfl_xor(vmx, off));
        if (t == 64) atomicMax(((int*)ws) + 1, __float_as_int(vmx));
    }
}

// ============================ k_main (v7) ============================
// 5 pairs: P1..P5. E: P1=Kst, P2/P5=Vt ping-pong(P5 first holds QM), P3=S, P4=KM.
// B: X->P1, Zr->P2, Zt->P3; KM/KV stashed to og[0..8191]. B2: fX cache; kv1
// partials -> P5f. D: Zt fixed P3; Zr/T1t/T2 rotate over {P2,P4,P5}; T1rm/oT in P1.
// F: KM reload->P1, KVt reload->P4, Zt=P3; qk->P5, w->P2; den partials in P5f.
__global__ __launch_bounds__(TPB_M, 8) void k_main(const float* __restrict__ q,
                                                   const float* __restrict__ k,
                                                   const float* __restrict__ v,
                                                   const float* __restrict__ ws,
                                                   float* __restrict__ out) {
    extern __shared__ f16 smu[];
    f16* P1h = smu;            f16* P1l = smu + 4096;
    f16* P2h = smu + 8192;     f16* P2l = smu + 12288;
    f16* P3h = smu + 16384;    f16* P3l = smu + 20480;
    f16* P4h = smu + 24576;    f16* P4l = smu + 28672;
    f16* P5h = smu + 32768;    f16* P5l = smu + 36864;
    float* P5f = (float*)P5h;   // f32 view: kv1 partials (B2/D-ph1), den partials (F)

    const int t = threadIdx.x, g = blockIdx.x;
    const int lane = t & 63, w = t >> 6;
    const int ti = w & 3, tj = w >> 2;
    const int fr = lane & 15, kg = lane >> 4;
    const int arow = (ti << 4) + fr;
    const int brow = (tj << 4) + fr;
    const int C = brow;
    const int Rb = (ti << 4) + (kg << 2);
    const float* Gq = q + (size_t)g * 16384;
    const float* Gk = k + (size_t)g * 16384;
    const float* Gv = v + (size_t)g * 16384;
    float* og = out + (size_t)g * 16384;

    // ---- prologue: QM->P5; K0->P1; V0t->P2 ----
    pool_global1024(Gq, P5h, P5l, t);
    {
        float4 k0 = *(const float4*)(Gk + (size_t)t * 4);
        float2 va0, vb0; ld_vt(Gv, t, va0, vb0);
        wr_rm(k0, P1h, P1l, t);
        wr_vt(va0, vb0, P2h, P2l, t);
    }
    __syncthreads();

    Frag fQM = ld_frag(P5h, P5l, arow, kg);   // read before any P5 write (ph1 of tile0)

    // ---- phase E: KV = activ(QM@K^T)@V ; pool KM ; kv1 partials in regs ----
    f32x4 kva = z4();
    float kv1p[4] = {0.f, 0.f, 0.f, 0.f};
    for (int tt = 0; tt < 4; ++tt) {
        f16* ch = (tt & 1) ? P5h : P2h; f16* cl_ = (tt & 1) ? P5l : P2l;  // Vt cur
        f16* nh = (tt & 1) ? P2h : P5h; f16* nl = (tt & 1) ? P2l : P5l;   // Vt next
        float4 krN; float2 vaN, vbN;
        if (tt < 3) {
            krN = *(const float4*)(Gk + (size_t)(tt + 1) * 4096 + (size_t)t * 4);
            ld_vt(Gv + (size_t)(tt + 1) * 4096, t, vaN, vbN);
        }
        // ph1: pool KM(tile); S = activ(QM@K^T) -> P3; kv1 partials
        if (t < 512) pool_lds512(P1h, P1l, P4h, P4l, t, tt);
        {
            Frag bK = ld_frag(P1h, P1l, brow, kg);
            f32x4 s = mm16_rr(fQM, bK, z4());
            float sv[4];
#pragma unroll
            for (int m = 0; m < 4; ++m) {
                sv[m] = activ_f(s[m]);
                float vs = sv[m];
                vs += __shfl_xor(vs, 1); vs += __shfl_xor(vs, 2);
                vs += __shfl_xor(vs, 4); vs += __shfl_xor(vs, 8);
                kv1p[m] += vs;
            }
            wfrag_rm(P3h, P3l, Rb, C, sv);
        }
        __syncthreads();
        // ph2: KV += S@Vt ; stage next K -> P1, next Vt -> other slot
        {
            Frag aS = ld_frag(P3h, P3l, arow, kg);
            Frag bV = ld_frag(ch, cl_, brow, kg);
            kva = mm16_rr(aS, bV, kva);
        }
        if (tt < 3) {
            wr_rm(krN, P1h, P1l, t);
            wr_vt(vaN, vbN, nh, nl, t);
        }
        __syncthreads();
    }

    // ---- phase B: stash KM,KV -> og ; X = activ(QM@KM^T) -> P1 ; Z-init -> P2,P3 ----
    {
        // stash KM pair (16KB raw) -> og[0..4095]
        const unsigned* sKM = (const unsigned*)P4h;
        unsigned* dKM = (unsigned*)og;
#pragma unroll
        for (int i = 0; i < 4; ++i) dKM[t + (i << 10)] = sKM[t + (i << 10)];
        // stash KV (f32 row-major) -> og[4096..8191]
#pragma unroll
        for (int m = 0; m < 4; ++m) og[4096 + (size_t)(Rb + m) * 64 + C] = kva[m];
        Frag fKMb = ld_frag(P4h, P4l, brow, kg);
        f32x4 x0 = mm16_rr(fQM, fKMb, z4());
        const float scale = ZS / (ws[0] * ws[1] + 1e-15f);
        float xv[4], zv[4];
#pragma unroll
        for (int m = 0; m < 4; ++m) { xv[m] = activ_f(x0[m]); zv[m] = xv[m] * scale; }
        wfrag_rm(P1h, P1l, Rb, C, xv);   // X row-major -> P1
        wfrag_t (P2h, P2l, Rb, C, zv);   // Zr (Z row-major) -> P2
        wfrag_rm(P3h, P3l, Rb, C, zv);   // Zt (Z^T, B-layout) -> P3
    }
    __syncthreads();

    // ---- B2: cache fX ; kv1 partials -> P5f ----
    Frag fX = ld_frag(P1h, P1l, arow, kg);
    if (fr == 0) {
#pragma unroll
        for (int m = 0; m < 4; ++m) P5f[(tj << 6) + Rb + m] = kv1p[m];
    }
    __syncthreads();

    // ---- phase D: 6 Newton-Schulz iterations, 5-pair rotation ----
    f16 *r0h = P2h, *r0l = P2l;   // Zr
    f16 *r1h = P4h, *r1l = P4l;   // T1t slot -> next Zr
    f16 *r2h = P5h, *r2l = P5l;   // T2 slot
    float kvC = 0.f;
#pragma unroll
    for (int it = 0; it < 6; ++it) {
        // ph1: T1 = X @ Z (acc carries ZS); iter0: grab kv1[C] from P5f
        Frag bz = ld_frag(P3h, P3l, brow, kg);
        f32x4 a1 = mm16_rr(fX, bz, z4());
        if (it == 0) kvC = P5f[C] + P5f[64 + C] + P5f[128 + C] + P5f[192 + C];
        float t1k[4];
#pragma unroll
        for (int m = 0; m < 4; ++m) t1k[m] = a1[m] * ZINV;
        wfrag_rm(P1h, P1l, Rb, C, t1k);   // T1 rm -> P1
        wfrag_t (r1h, r1l, Rb, C, t1k);   // T1^T -> r1
        __syncthreads();
        // ph2: T2 = T1 @ T1 -> r2
        Frag aT1 = ld_frag(P1h, P1l, arow, kg);
        Frag bT1 = ld_frag(r1h, r1l, brow, kg);
        f32x4 a2 = mm16_rr(aT1, bT1, z4());
        float t2k[4];
#pragma unroll
        for (int m = 0; m < 4; ++m) t2k[m] = a2[m];
        wfrag_rm(r2h, r2l, Rb, C, t2k);
        __syncthreads();
        // ph3: T4 = T2 @ T1 ; outer -> P1 (T-layout; T1rm dead)
        Frag aT2 = ld_frag(r2h, r2l, arow, kg);
        f32x4 a3 = mm16_rr(aT2, bT1, z4());
        float ov[4];
#pragma unroll
        for (int m = 0; m < 4; ++m) {
            const int R = Rb + m;
            ov[m] = ((R == C) ? 13.f : 0.f) - 15.f * t1k[m] + 7.f * t2k[m] - a3[m];
        }
        wfrag_t(P1h, P1l, Rb, C, ov);
        __syncthreads();
        // ph4: Znew = 0.25 * Z @ outer -> rm into r1 (T1t dead), t into P3 (Zt dead)
        Frag aZ = ld_frag(r0h, r0l, arow, kg);
        Frag bO = ld_frag(P1h, P1l, brow, kg);
        f32x4 a4 = mm16_rr(aZ, bO, z4());
        float zk[4];
#pragma unroll
        for (int m = 0; m < 4; ++m) zk[m] = 0.25f * a4[m];
        wfrag_rm(r1h, r1l, Rb, C, zk);
        wfrag_t (P3h, P3l, Rb, C, zk);
        __syncthreads();
        // rotate: r0 <- r1 <- r2 <- r0
        f16 *th, *tl;
        th = r0h; tl = r0l;
        r0h = r1h; r0l = r1l;
        r1h = r2h; r1l = r2l;
        r2h = th;  r2l = tl;
    }
    // final: Zt = P3 (P2 holds Zr, unused in F)

    // ---- F reload: KM og -> P1 (raw), KV og -> P4 as KV^T (B-layout) ----
    {
        const unsigned* sKM = (const unsigned*)og;
        unsigned* dKM = (unsigned*)P1h;
#pragma unroll
        for (int i = 0; i < 4; ++i) dKM[t + (i << 10)] = sKM[t + (i << 10)];
        float4 kvv = *(const float4*)(og + 4096 + (size_t)t * 4);
        const int l = t >> 4, e0 = (t & 15) << 2;
        split_w(P4h, P4l, e0 + 0, l, kvv.x);
        split_w(P4h, P4l, e0 + 1, l, kvv.y);
        split_w(P4h, P4l, e0 + 2, l, kvv.z);
        split_w(P4h, P4l, e0 + 3, l, kvv.w);
    }
    __syncthreads();

    // ---- phase F: out = (activ(q@KM^T) @ Z @ KV) / den ; 4 tiles ----
    for (int tt = 0; tt < 4; ++tt) {
        // phA: qk = activ(q_global @ KM^T) -> P5
        {
            Frag aQ = mk_gfrag(Gq + (size_t)((tt << 6) + arow) * 64, kg);
            Frag bKM = ld_frag(P1h, P1l, brow, kg);
            f32x4 q0 = mm16_rr(aQ, bKM, z4());
            float qv[4];
#pragma unroll
            for (int m = 0; m < 4; ++m) qv[m] = activ_f(q0[m]);
            wfrag_rm(P5h, P5l, Rb, C, qv);
        }
        __syncthreads();
        // phB: w = qk @ Z -> P2 ; den partials in regs
        float dp[4];
        {
            Frag aK = ld_frag(P5h, P5l, arow, kg);
            Frag bZt = ld_frag(P3h, P3l, brow, kg);
            f32x4 w0 = mm16_rr(aK, bZt, z4());
            float wv[4];
#pragma unroll
            for (int m = 0; m < 4; ++m) {
                wv[m] = w0[m] * ZINV;
                float d_ = wv[m] * kvC;
                d_ += __shfl_xor(d_, 1); d_ += __shfl_xor(d_, 2);
                d_ += __shfl_xor(d_, 4); d_ += __shfl_xor(d_, 8);
                dp[m] = d_;
            }
            wfrag_rm(P2h, P2l, Rb, C, wv);
        }
        __syncthreads();
        // phC (tiny): den partials -> P5f (qk dead)
        if (fr == 0) {
#pragma unroll
            for (int m = 0; m < 4; ++m) P5f[(tj << 6) + Rb + m] = dp[m];
        }
        __syncthreads();
        // phD: prod = w @ KV ; divide ; store
        {
            Frag aW = ld_frag(P2h, P2l, arow, kg);
            Frag bKV = ld_frag(P4h, P4l, brow, kg);
            f32x4 p0 = mm16_rr(aW, bKV, z4());
#pragma unroll
            for (int m = 0; m < 4; ++m) {
                const int R = Rb + m;
                const float den = P5f[R] + P5f[64 + R] + P5f[128 + R] + P5f[192 + R];
                og[(size_t)((tt << 6) + R) * 64 + C] = p0[m] / (den + 1e-12f);
            }
        }
        __syncthreads();
    }
}

extern "C" void kernel_launch(void* const* d_in, const int* in_sizes, int n_in,
                              void* d_out, int out_size, void* d_ws, size_t ws_size,
                              hipStream_t stream) {
    const float* q = (const float*)d_in[0];
    const float* k = (const float*)d_in[1];
    const float* v = (const float*)d_in[2];
    float* out = (float*)d_out;
    float* ws  = (float*)d_ws;
    (void)in_sizes; (void)n_in; (void)out_size; (void)ws_size;

    hipFuncSetAttribute((const void*)k_main,
                        hipFuncAttributeMaxDynamicSharedMemorySize, SMEM_BYTES);

    k_init<<<1, 64, 0, stream>>>(ws);
    k_reduce<<<G_TOT, TPB_R, 0, stream>>>(q, k, ws);
    k_main<<<G_TOT, TPB_M, SMEM_BYTES, stream>>>(q, k, v, ws, out);
}

// Round 10
// 1042.146 us; speedup vs baseline: 1.6123x; 1.6123x over previous
//
#include <hip/hip_runtime.h>
#include <math.h>

// PnPNystra attention, MFMA v8: 512-thr / 8-wave k_main, 2 blocks/CU
// (81920 B LDS x2 = 160 KiB), launch_bounds(512,4) -> VGPR<=128 (no spills),
// dual 16x16 tiles per wave, 5 plane-pair choreography, KM/KV stash to og.
// Numerics: split f16 (v ~= h + l/2048), 3x mfma_f32_16x16x32_f16, Z scaled 1024.
// G=4096 groups, N=256, d=64, L=64.

#define G_TOT 4096
#define TPB_R 256
#define TPB_M 512
typedef _Float16 f16;
typedef __attribute__((ext_vector_type(2))) _Float16 f16x2;
typedef __attribute__((ext_vector_type(4))) _Float16 f16x4;
typedef __attribute__((ext_vector_type(8))) _Float16 f16x8;
typedef __attribute__((ext_vector_type(4))) float f32x4;
typedef __attribute__((ext_vector_type(16))) float f32x16;

#define NPLANES 10
#define SMEM_BYTES (NPLANES * 4096 * 2)  // 81920 B -> 2 blocks/CU

#define LSCALE 2048.0f
#define LINV   (1.0f / 2048.0f)
#define ZS     1024.0f
#define ZINV   (1.0f / 1024.0f)

struct HL { f16 h, l; };
__device__ __forceinline__ HL split2(float v) {
    HL r;
    r.h = (f16)v;
    r.l = (f16)((v - (float)r.h) * LSCALE);
    return r;
}
__device__ __forceinline__ float join2(f16 h, f16 l) {
    return (float)h + (float)l * LINV;
}
__device__ __forceinline__ int swi(int r, int c) {
    return (r << 6) + (c ^ ((r & 7) << 3));
}
__device__ __forceinline__ float activ_f(float x) {
    return __expf(fminf(x, 5.0f)) + fmaxf(x - 5.0f, 0.0f);
}
__device__ __forceinline__ float activ_r(float x) {
    return expf(fminf(x, 5.0f)) + fmaxf(x - 5.0f, 0.0f);
}
__device__ __forceinline__ void split_w(f16* Ph, f16* Pl, int r, int c, float v) {
    HL s = split2(v);
    const int o = swi(r, c);
    Ph[o] = s.h;
    Pl[o] = s.l;
}
__device__ __forceinline__ f16x2 mk2(f16 a, f16 b) { f16x2 r; r[0]=a; r[1]=b; return r; }
__device__ __forceinline__ f16x4 mk4(f16 a, f16 b, f16 c, f16 d) { f16x4 r; r[0]=a;r[1]=b;r[2]=c;r[3]=d; return r; }
__device__ __forceinline__ f32x4 z4() { f32x4 z = {0.f,0.f,0.f,0.f}; return z; }
__device__ __forceinline__ f32x16 z16() {
    f32x16 z;
#pragma unroll
    for (int i = 0; i < 16; ++i) z[i] = 0.f;
    return z;
}

struct Frag { f16x8 h[2], l[2]; };

__device__ __forceinline__ Frag ld_frag(const f16* __restrict__ Ph,
                                        const f16* __restrict__ Pl,
                                        int row, int kg) {
    Frag f;
    const int base = row << 6, x = (row & 7) << 3;
#pragma unroll
    for (int s = 0; s < 2; ++s) {
        const int o = base + ((((s << 5) + (kg << 3))) ^ x);
        f.h[s] = *(const f16x8*)(Ph + o);
        f.l[s] = *(const f16x8*)(Pl + o);
    }
    return f;
}

// A-frag built straight from a global f32 row (no LDS staging)
__device__ __forceinline__ Frag mk_gfrag(const float* __restrict__ row, int kg) {
    Frag f;
#pragma unroll
    for (int s = 0; s < 2; ++s) {
        const float* p = row + (s << 5) + (kg << 3);
        float4 a = *(const float4*)p;
        float4 b = *(const float4*)(p + 4);
        HL s0 = split2(a.x), s1 = split2(a.y), s2 = split2(a.z), s3 = split2(a.w);
        HL s4 = split2(b.x), s5 = split2(b.y), s6 = split2(b.z), s7 = split2(b.w);
        f16x8 h, l;
        h[0]=s0.h; h[1]=s1.h; h[2]=s2.h; h[3]=s3.h; h[4]=s4.h; h[5]=s5.h; h[6]=s6.h; h[7]=s7.h;
        l[0]=s0.l; l[1]=s1.l; l[2]=s2.l; l[3]=s3.l; l[4]=s4.l; l[5]=s5.l; l[6]=s6.l; l[7]=s7.l;
        f.h[s] = h; f.l[s] = l;
    }
    return f;
}

__device__ __forceinline__ f32x4 mm16_rr(const Frag& A, const Frag& B, f32x4 acc) {
    f32x4 ax1 = z4(), ax2 = z4();
#pragma unroll
    for (int s = 0; s < 2; ++s) {
        acc = __builtin_amdgcn_mfma_f32_16x16x32_f16(A.h[s], B.h[s], acc, 0, 0, 0);
        ax1 = __builtin_amdgcn_mfma_f32_16x16x32_f16(A.h[s], B.l[s], ax1, 0, 0, 0);
        ax2 = __builtin_amdgcn_mfma_f32_16x16x32_f16(A.l[s], B.h[s], ax2, 0, 0, 0);
    }
    acc += (ax1 + ax2) * LINV;
    return acc;
}

__device__ __forceinline__ void wfrag_rm(f16* Ph, f16* Pl, int Rb, int C, const float* v) {
#pragma unroll
    for (int m = 0; m < 4; ++m) split_w(Ph, Pl, Rb + m, C, v[m]);
}
__device__ __forceinline__ void wfrag_t(f16* Ph, f16* Pl, int Rb, int C, const float* v) {
    const int o = swi(C, Rb);
    HL s0 = split2(v[0]), s1 = split2(v[1]), s2 = split2(v[2]), s3 = split2(v[3]);
    *(f16x4*)(Ph + o) = mk4(s0.h, s1.h, s2.h, s3.h);
    *(f16x4*)(Pl + o) = mk4(s0.l, s1.l, s2.l, s3.l);
}

// ---- staging helpers (512 threads) ----
// write float4 #f (f in [0,1024)) of a row-major 64x64 tile
__device__ __forceinline__ void wr_rm_f(float4 vv, f16* Ph, f16* Pl, int f) {
    const int r = f >> 4, c4 = (f & 15) << 2;
    const int o = swi(r, c4);
    HL s0 = split2(vv.x), s1 = split2(vv.y), s2 = split2(vv.z), s3 = split2(vv.w);
    *(f16x4*)(Ph + o) = mk4(s0.h, s1.h, s2.h, s3.h);
    *(f16x4*)(Pl + o) = mk4(s0.l, s1.l, s2.l, s3.l);
}
// transposed V stage (512 thr): thread owns rows n0,n0+1 at cols e0..e0+3
__device__ __forceinline__ void ld_vt(const float* __restrict__ src, int t,
                                      float4& va, float4& vb) {
    const int n0 = (t >> 4) << 1, e0 = (t & 15) << 2;
    va = *(const float4*)(src + (size_t)n0 * 64 + e0);
    vb = *(const float4*)(src + (size_t)(n0 + 1) * 64 + e0);
}
__device__ __forceinline__ void wr_vt(float4 va, float4 vb, f16* Ph, f16* Pl, int t) {
    const int n0 = (t >> 4) << 1, e0 = (t & 15) << 2;
    const float* a = (const float*)&va;
    const float* b = (const float*)&vb;
#pragma unroll
    for (int j = 0; j < 4; ++j) {
        HL sa = split2(a[j]), sb = split2(b[j]);
        const int o = swi(e0 + j, n0);
        *(f16x2*)(Ph + o) = mk2(sa.h, sb.h);
        *(f16x2*)(Pl + o) = mk2(sa.l, sb.l);
    }
}
// pool 2x2-mean landmarks from global fp32 [256][64] (512 thr: L=t>>3, 8 d's)
__device__ __forceinline__ void pool_global512(const float* __restrict__ src,
                                               f16* Ph, f16* Pl, int t) {
    const int L = t >> 3, d0 = (t & 7) << 3;
    const int nb = ((L >> 3) << 5) + ((L & 7) << 1);
    const float* p = src + (size_t)nb * 64 + d0;
    float4 a0 = *(const float4*)p;           float4 a1 = *(const float4*)(p + 4);
    float4 b0 = *(const float4*)(p + 64);    float4 b1 = *(const float4*)(p + 68);
    float4 c0 = *(const float4*)(p + 1024);  float4 c1 = *(const float4*)(p + 1028);
    float4 d0_ = *(const float4*)(p + 1088); float4 d1 = *(const float4*)(p + 1092);
    HL s0 = split2(0.25f * (a0.x + b0.x + c0.x + d0_.x));
    HL s1 = split2(0.25f * (a0.y + b0.y + c0.y + d0_.y));
    HL s2 = split2(0.25f * (a0.z + b0.z + c0.z + d0_.z));
    HL s3 = split2(0.25f * (a0.w + b0.w + c0.w + d0_.w));
    HL s4 = split2(0.25f * (a1.x + b1.x + c1.x + d1.x));
    HL s5 = split2(0.25f * (a1.y + b1.y + c1.y + d1.y));
    HL s6 = split2(0.25f * (a1.z + b1.z + c1.z + d1.z));
    HL s7 = split2(0.25f * (a1.w + b1.w + c1.w + d1.w));
    const int o = swi(L, d0);
    *(f16x4*)(Ph + o)     = mk4(s0.h, s1.h, s2.h, s3.h);
    *(f16x4*)(Ph + o + 4) = mk4(s4.h, s5.h, s6.h, s7.h);
    *(f16x4*)(Pl + o)     = mk4(s0.l, s1.l, s2.l, s3.l);
    *(f16x4*)(Pl + o + 4) = mk4(s4.l, s5.l, s6.l, s7.l);
}
// pool landmarks of one staged K tile (512 thr)
__device__ __forceinline__ void pool_lds512(const f16* Kh, const f16* Kl,
                                            f16* Ph, f16* Pl, int t, int tt) {
    const int ll = t >> 5, d0 = (t & 31) << 1;
    const int rb = ((ll >> 3) << 5) + ((ll & 7) << 1);
    float s0 = 0.f, s1 = 0.f;
#pragma unroll
    for (int rr = 0; rr < 4; ++rr) {
        const int r = rb + (rr & 1) + ((rr >> 1) << 4);
        const int o = swi(r, d0);
        f16x2 h = *(const f16x2*)(Kh + o);
        f16x2 l = *(const f16x2*)(Kl + o);
        s0 += join2(h[0], l[0]);
        s1 += join2(h[1], l[1]);
    }
    const int L = (tt << 4) + ll;
    HL p0 = split2(0.25f * s0), p1 = split2(0.25f * s1);
    const int o = swi(L, d0);
    *(f16x2*)(Ph + o) = mk2(p0.h, p1.h);
    *(f16x2*)(Pl + o) = mk2(p0.l, p1.l);
}

// ---- k_reduce helpers (unchanged) ----
__device__ __forceinline__ f32x16 mm64q(const f16* __restrict__ Ah, const f16* __restrict__ Al,
                                        const f16* __restrict__ Bh, const f16* __restrict__ Bl,
                                        int lane, int wr, int wc, f32x16 acc) {
    const int cl = lane & 31, hh = lane >> 5;
    const int ar = (wr << 5) + cl, br = (wc << 5) + cl;
    const int abase = ar << 6, axor = (ar & 7) << 3;
    const int bbase = br << 6, bxor = (br & 7) << 3;
    f32x16 ax1 = z16();
    f32x16 ax2 = z16();
#pragma unroll
    for (int ks = 0; ks < 4; ++ks) {
        const int k0 = (ks << 4) + (hh << 3);
        const int ao = abase + (k0 ^ axor);
        const int bo = bbase + (k0 ^ bxor);
        f16x8 a_h = *(const f16x8*)(Ah + ao);
        f16x8 a_l = *(const f16x8*)(Al + ao);
        f16x8 b_h = *(const f16x8*)(Bh + bo);
        f16x8 b_l = *(const f16x8*)(Bl + bo);
        acc = __builtin_amdgcn_mfma_f32_32x32x16_f16(a_h, b_h, acc, 0, 0, 0);
        ax1 = __builtin_amdgcn_mfma_f32_32x32x16_f16(a_h, b_l, ax1, 0, 0, 0);
        ax2 = __builtin_amdgcn_mfma_f32_32x32x16_f16(a_l, b_h, ax2, 0, 0, 0);
    }
    acc += (ax1 + ax2) * LINV;
    return acc;
}
__device__ __forceinline__ void pool_global_r(const float* __restrict__ src,
                                              f16* Ph, f16* Pl, int t) {
    const int ll = t >> 4, d0 = (t & 15) << 2;
    const int rb = ((ll >> 3) << 5) + ((ll & 7) << 1);
#pragma unroll
    for (int tt = 0; tt < 4; ++tt) {
        const float* p = src + (size_t)((tt << 6) + rb) * 64 + d0;
        float4 a = *(const float4*)p;
        float4 b = *(const float4*)(p + 64);
        float4 c = *(const float4*)(p + 1024);
        float4 d = *(const float4*)(p + 1088);
        const int L = (tt << 4) + ll;
        split_w(Ph, Pl, L, d0 + 0, 0.25f * (a.x + b.x + c.x + d.x));
        split_w(Ph, Pl, L, d0 + 1, 0.25f * (a.y + b.y + c.y + d.y));
        split_w(Ph, Pl, L, d0 + 2, 0.25f * (a.z + b.z + c.z + d.z));
        split_w(Ph, Pl, L, d0 + 3, 0.25f * (a.w + b.w + c.w + d.w));
    }
}

#define WAVE_SUM32(v)            \
    v += __shfl_xor(v, 1);       \
    v += __shfl_xor(v, 2);       \
    v += __shfl_xor(v, 4);       \
    v += __shfl_xor(v, 8);       \
    v += __shfl_xor(v, 16);

__global__ void k_init(float* ws) {
    if (threadIdx.x < 2) ws[threadIdx.x] = 0.0f;
}

__global__ __launch_bounds__(TPB_R) void k_reduce(const float* __restrict__ q,
                                                  const float* __restrict__ k,
                                                  float* __restrict__ ws) {
    __shared__ f16 pls[4 * 4096];
    __shared__ float rowS[64], colS[64];
    const int t = threadIdx.x, g = blockIdx.x;
    const int lane = t & 63, wv = t >> 6, wr = wv >> 1, wc = wv & 1;
    const int cl = lane & 31, hh = lane >> 5;
    if (t < 64) rowS[t] = 0.f;
    else if (t < 128) colS[t - 64] = 0.f;
    pool_global_r(q + (size_t)g * 16384, pls, pls + 4096, t);
    pool_global_r(k + (size_t)g * 16384, pls + 8192, pls + 12288, t);
    __syncthreads();
    f32x16 a = mm64q(pls, pls + 4096, pls + 8192, pls + 12288, lane, wr, wc, z16());
    float colp = 0.f;
#pragma unroll
    for (int m = 0; m < 16; ++m) {
        float x = activ_r(a[m]);
        const int R = (wr << 5) + (m & 3) + ((m >> 2) << 3) + (hh << 2);
        float vs = x;
        WAVE_SUM32(vs)
        if (cl == 0) atomicAdd(&rowS[R], vs);
        colp += x;
    }
    colp += __shfl_xor(colp, 32);
    if (hh == 0) atomicAdd(&colS[(wc << 5) + cl], colp);
    __syncthreads();
    if (t < 64) {
        float vmx = rowS[t];
        for (int off = 1; off < 64; off <<= 1) vmx = fmaxf(vmx, __shfl_xor(vmx, off));
        if (t == 0) atomicMax((int*)ws, __float_as_int(vmx));
    } else if (t < 128) {
        float vmx = colS[t - 64];
        for (int off = 1; off < 64; off <<= 1) vmx = fmaxf(vmx, __shfl_xor(vmx, off));
        if (t == 64) atomicMax(((int*)ws) + 1, __float_as_int(vmx));
    }
}

// ============================ k_main (v8) ============================
// 8 waves, each owns tile-row ti = w&3 and tile-cols {tjh*32, tjh*32+16}, tjh = w>>2.
// 5 pairs P1..P5: E: P1=Kst, P2/P5=Vt ping-pong (P5 first=QM), P3=S, P4=KM.
// B: X->P1, Zr->P2, Zt->P3; KM/KV stash->og. D: Zt=P3 fixed, {P2,P4,P5} rotate,
// T1rm/oT in P1. F: KM reload->P1, KVt->P4; qk->P5, w->P2; kv1/den partials in P5f.
__global__ __launch_bounds__(TPB_M, 4) void k_main(const float* __restrict__ q,
                                                   const float* __restrict__ k,
                                                   const float* __restrict__ v,
                                                   const float* __restrict__ ws,
                                                   float* __restrict__ out) {
    extern __shared__ f16 smu[];
    f16* P1h = smu;            f16* P1l = smu + 4096;
    f16* P2h = smu + 8192;     f16* P2l = smu + 12288;
    f16* P3h = smu + 16384;    f16* P3l = smu + 20480;
    f16* P4h = smu + 24576;    f16* P4l = smu + 28672;
    f16* P5h = smu + 32768;    f16* P5l = smu + 36864;
    float* P5f = (float*)P5h;   // f32 view: kv1 partials / den partials (2x64)

    const int t = threadIdx.x, g = blockIdx.x;
    const int lane = t & 63, w = t >> 6;          // 8 waves
    const int ti = w & 3, tjh = w >> 2;           // tile row; col-half
    const int fr = lane & 15, kg = lane >> 4;
    const int arow = (ti << 4) + fr;
    const int brow0 = (tjh << 5) + fr, brow1 = brow0 + 16;
    const int C0 = brow0, C1 = brow1;
    const int Rb = (ti << 4) + (kg << 2);
    const float* Gq = q + (size_t)g * 16384;
    const float* Gk = k + (size_t)g * 16384;
    const float* Gv = v + (size_t)g * 16384;
    float* og = out + (size_t)g * 16384;

    // ---- prologue: QM->P5; K0->P1; V0t->P2 ----
    pool_global512(Gq, P5h, P5l, t);
    {
        float4 k0a = *(const float4*)(Gk + (size_t)t * 4);
        float4 k0b = *(const float4*)(Gk + (size_t)(t + 512) * 4);
        float4 va0, vb0; ld_vt(Gv, t, va0, vb0);
        wr_rm_f(k0a, P1h, P1l, t);
        wr_rm_f(k0b, P1h, P1l, t + 512);
        wr_vt(va0, vb0, P2h, P2l, t);
    }
    __syncthreads();

    Frag fQM = ld_frag(P5h, P5l, arow, kg);   // cached before P5 is overwritten

    // ---- phase E: KV = activ(QM@K^T)@V ; pool KM ; kv1 partials in regs ----
    f32x4 kva0 = z4(), kva1 = z4();
    float kv1p[4] = {0.f, 0.f, 0.f, 0.f};
    for (int tt = 0; tt < 4; ++tt) {
        f16* ch = (tt & 1) ? P5h : P2h; f16* cl_ = (tt & 1) ? P5l : P2l;  // Vt cur
        f16* nh = (tt & 1) ? P2h : P5h; f16* nl = (tt & 1) ? P2l : P5l;   // Vt next
        float4 krA, krB, vaN, vbN;
        if (tt < 3) {
            const float* nk = Gk + (size_t)(tt + 1) * 4096;
            krA = *(const float4*)(nk + (size_t)t * 4);
            krB = *(const float4*)(nk + (size_t)(t + 512) * 4);
            ld_vt(Gv + (size_t)(tt + 1) * 4096, t, vaN, vbN);
        }
        // ph1: pool KM(tile); S = activ(QM@K^T) -> P3 (2 tiles); kv1 partials
        pool_lds512(P1h, P1l, P4h, P4l, t, tt);
        {
            Frag bK0 = ld_frag(P1h, P1l, brow0, kg);
            Frag bK1 = ld_frag(P1h, P1l, brow1, kg);
            f32x4 s0 = mm16_rr(fQM, bK0, z4());
            f32x4 s1 = mm16_rr(fQM, bK1, z4());
            float sv0[4], sv1[4];
#pragma unroll
            for (int m = 0; m < 4; ++m) {
                sv0[m] = activ_f(s0[m]);
                sv1[m] = activ_f(s1[m]);
                float vs = sv0[m] + sv1[m];
                vs += __shfl_xor(vs, 1); vs += __shfl_xor(vs, 2);
                vs += __shfl_xor(vs, 4); vs += __shfl_xor(vs, 8);
                kv1p[m] += vs;
            }
            wfrag_rm(P3h, P3l, Rb, C0, sv0);
            wfrag_rm(P3h, P3l, Rb, C1, sv1);
        }
        __syncthreads();
        // ph2: KV += S@Vt ; stage next K -> P1, next Vt -> other slot
        {
            Frag aS = ld_frag(P3h, P3l, arow, kg);
            Frag bV0 = ld_frag(ch, cl_, brow0, kg);
            Frag bV1 = ld_frag(ch, cl_, brow1, kg);
            kva0 = mm16_rr(aS, bV0, kva0);
            kva1 = mm16_rr(aS, bV1, kva1);
        }
        if (tt < 3) {
            wr_rm_f(krA, P1h, P1l, t);
            wr_rm_f(krB, P1h, P1l, t + 512);
            wr_vt(vaN, vbN, nh, nl, t);
        }
        __syncthreads();
    }

    // ---- phase B: stash KM,KV -> og ; X = activ(QM@KM^T) -> P1 ; Z-init ----
    {
        const unsigned* sKM = (const unsigned*)P4h;
        unsigned* dKM = (unsigned*)og;
#pragma unroll
        for (int i = 0; i < 8; ++i) dKM[t + (i << 9)] = sKM[t + (i << 9)];
#pragma unroll
        for (int m = 0; m < 4; ++m) {
            og[4096 + (size_t)(Rb + m) * 64 + C0] = kva0[m];
            og[4096 + (size_t)(Rb + m) * 64 + C1] = kva1[m];
        }
        Frag bKM0 = ld_frag(P4h, P4l, brow0, kg);
        Frag bKM1 = ld_frag(P4h, P4l, brow1, kg);
        f32x4 x0 = mm16_rr(fQM, bKM0, z4());
        f32x4 x1 = mm16_rr(fQM, bKM1, z4());
        const float scale = ZS / (ws[0] * ws[1] + 1e-15f);
        float xv0[4], xv1[4], zv0[4], zv1[4];
#pragma unroll
        for (int m = 0; m < 4; ++m) {
            xv0[m] = activ_f(x0[m]); zv0[m] = xv0[m] * scale;
            xv1[m] = activ_f(x1[m]); zv1[m] = xv1[m] * scale;
        }
        wfrag_rm(P1h, P1l, Rb, C0, xv0);  wfrag_rm(P1h, P1l, Rb, C1, xv1);   // X
        wfrag_t (P2h, P2l, Rb, C0, zv0);  wfrag_t (P2h, P2l, Rb, C1, zv1);   // Zr
        wfrag_rm(P3h, P3l, Rb, C0, zv0);  wfrag_rm(P3h, P3l, Rb, C1, zv1);   // Zt
    }
    __syncthreads();

    // ---- B2: cache fX ; kv1 partials -> P5f[tjh*64 + R] ----
    Frag fX = ld_frag(P1h, P1l, arow, kg);
    if (fr == 0) {
#pragma unroll
        for (int m = 0; m < 4; ++m) P5f[(tjh << 6) + Rb + m] = kv1p[m];
    }
    __syncthreads();

    // ---- phase D: 6 Newton-Schulz iterations, 5-pair rotation ----
    f16 *r0h = P2h, *r0l = P2l;   // Zr
    f16 *r1h = P4h, *r1l = P4l;   // T1t slot -> next Zr
    f16 *r2h = P5h, *r2l = P5l;   // T2 slot
    float kvC0 = 0.f, kvC1 = 0.f;
#pragma unroll
    for (int it = 0; it < 6; ++it) {
        // ph1: T1 = X @ Z (acc carries ZS); it0: grab kv1 from P5f before r2 write
        Frag bz0 = ld_frag(P3h, P3l, brow0, kg);
        Frag bz1 = ld_frag(P3h, P3l, brow1, kg);
        f32x4 a10 = mm16_rr(fX, bz0, z4());
        f32x4 a11 = mm16_rr(fX, bz1, z4());
        if (it == 0) {
            kvC0 = P5f[C0] + P5f[64 + C0];
            kvC1 = P5f[C1] + P5f[64 + C1];
        }
        float t1k0[4], t1k1[4];
#pragma unroll
        for (int m = 0; m < 4; ++m) { t1k0[m] = a10[m] * ZINV; t1k1[m] = a11[m] * ZINV; }
        wfrag_rm(P1h, P1l, Rb, C0, t1k0);  wfrag_rm(P1h, P1l, Rb, C1, t1k1);
        wfrag_t (r1h, r1l, Rb, C0, t1k0);  wfrag_t (r1h, r1l, Rb, C1, t1k1);
        __syncthreads();
        // ph2: T2 = T1 @ T1 -> r2 (cache bT1 for ph3)
        Frag aT1 = ld_frag(P1h, P1l, arow, kg);
        Frag bT10 = ld_frag(r1h, r1l, brow0, kg);
        Frag bT11 = ld_frag(r1h, r1l, brow1, kg);
        f32x4 a20 = mm16_rr(aT1, bT10, z4());
        f32x4 a21 = mm16_rr(aT1, bT11, z4());
        float t2k0[4], t2k1[4];
#pragma unroll
        for (int m = 0; m < 4; ++m) { t2k0[m] = a20[m]; t2k1[m] = a21[m]; }
        wfrag_rm(r2h, r2l, Rb, C0, t2k0);  wfrag_rm(r2h, r2l, Rb, C1, t2k1);
        __syncthreads();
        // ph3: T4 = T2 @ T1 ; outer -> P1 (T-layout)
        Frag aT2 = ld_frag(r2h, r2l, arow, kg);
        f32x4 a30 = mm16_rr(aT2, bT10, z4());
        f32x4 a31 = mm16_rr(aT2, bT11, z4());
        float ov0[4], ov1[4];
#pragma unroll
        for (int m = 0; m < 4; ++m) {
            const int R = Rb + m;
            ov0[m] = ((R == C0) ? 13.f : 0.f) - 15.f * t1k0[m] + 7.f * t2k0[m] - a30[m];
            ov1[m] = ((R == C1) ? 13.f : 0.f) - 15.f * t1k1[m] + 7.f * t2k1[m] - a31[m];
        }
        wfrag_t(P1h, P1l, Rb, C0, ov0);  wfrag_t(P1h, P1l, Rb, C1, ov1);
        __syncthreads();
        // ph4: Znew = 0.25 * Z @ outer -> rm r1, t P3
        Frag aZ = ld_frag(r0h, r0l, arow, kg);
        Frag bO0 = ld_frag(P1h, P1l, brow0, kg);
        Frag bO1 = ld_frag(P1h, P1l, brow1, kg);
        f32x4 a40 = mm16_rr(aZ, bO0, z4());
        f32x4 a41 = mm16_rr(aZ, bO1, z4());
        float zk0[4], zk1[4];
#pragma unroll
        for (int m = 0; m < 4; ++m) { zk0[m] = 0.25f * a40[m]; zk1[m] = 0.25f * a41[m]; }
        wfrag_rm(r1h, r1l, Rb, C0, zk0);  wfrag_rm(r1h, r1l, Rb, C1, zk1);
        wfrag_t (P3h, P3l, Rb, C0, zk0);  wfrag_t (P3h, P3l, Rb, C1, zk1);
        __syncthreads();
        f16 *th, *tl;
        th = r0h; tl = r0l;
        r0h = r1h; r0l = r1l;
        r1h = r2h; r1l = r2l;
        r2h = th;  r2l = tl;
    }
    // final Zt = P3

    // ---- F reload: KM og -> P1 (raw), KV og -> P4 as KV^T (B-layout) ----
    {
        const unsigned* sKM = (const unsigned*)og;
        unsigned* dKM = (unsigned*)P1h;
#pragma unroll
        for (int i = 0; i < 8; ++i) dKM[t + (i << 9)] = sKM[t + (i << 9)];
#pragma unroll
        for (int i = 0; i < 2; ++i) {
            const int f = t + (i << 9);
            float4 kvv = *(const float4*)(og + 4096 + (size_t)f * 4);
            const int l = f >> 4, e0 = (f & 15) << 2;
            split_w(P4h, P4l, e0 + 0, l, kvv.x);
            split_w(P4h, P4l, e0 + 1, l, kvv.y);
            split_w(P4h, P4l, e0 + 2, l, kvv.z);
            split_w(P4h, P4l, e0 + 3, l, kvv.w);
        }
    }
    __syncthreads();

    // ---- phase F: out = (activ(q@KM^T) @ Z @ KV) / den ; 4 q-tiles ----
    for (int tt = 0; tt < 4; ++tt) {
        // phA: qk = activ(q_global @ KM^T) -> P5
        {
            Frag aQ = mk_gfrag(Gq + (size_t)((tt << 6) + arow) * 64, kg);
            Frag bKM0 = ld_frag(P1h, P1l, brow0, kg);
            Frag bKM1 = ld_frag(P1h, P1l, brow1, kg);
            f32x4 q0 = mm16_rr(aQ, bKM0, z4());
            f32x4 q1 = mm16_rr(aQ, bKM1, z4());
            float qv0[4], qv1[4];
#pragma unroll
            for (int m = 0; m < 4; ++m) { qv0[m] = activ_f(q0[m]); qv1[m] = activ_f(q1[m]); }
            wfrag_rm(P5h, P5l, Rb, C0, qv0);
            wfrag_rm(P5h, P5l, Rb, C1, qv1);
        }
        __syncthreads();
        // phB: w = qk @ Z -> P2 ; den partials in regs
        float dp[4];
        {
            Frag aK = ld_frag(P5h, P5l, arow, kg);
            Frag bZt0 = ld_frag(P3h, P3l, brow0, kg);
            Frag bZt1 = ld_frag(P3h, P3l, brow1, kg);
            f32x4 w0 = mm16_rr(aK, bZt0, z4());
            f32x4 w1 = mm16_rr(aK, bZt1, z4());
            float wv0[4], wv1[4];
#pragma unroll
            for (int m = 0; m < 4; ++m) {
                wv0[m] = w0[m] * ZINV;
                wv1[m] = w1[m] * ZINV;
                float d_ = wv0[m] * kvC0 + wv1[m] * kvC1;
                d_ += __shfl_xor(d_, 1); d_ += __shfl_xor(d_, 2);
                d_ += __shfl_xor(d_, 4); d_ += __shfl_xor(d_, 8);
                dp[m] = d_;
            }
            wfrag_rm(P2h, P2l, Rb, C0, wv0);
            wfrag_rm(P2h, P2l, Rb, C1, wv1);
        }
        __syncthreads();
        // phC (tiny): den partials -> P5f (qk dead)
        if (fr == 0) {
#pragma unroll
            for (int m = 0; m < 4; ++m) P5f[(tjh << 6) + Rb + m] = dp[m];
        }
        __syncthreads();
        // phD: prod = w @ KV ; divide ; store
        {
            Frag aW = ld_frag(P2h, P2l, arow, kg);
            Frag bKV0 = ld_frag(P4h, P4l, brow0, kg);
            Frag bKV1 = ld_frag(P4h, P4l, brow1, kg);
            f32x4 p0 = mm16_rr(aW, bKV0, z4());
            f32x4 p1 = mm16_rr(aW, bKV1, z4());
#pragma unroll
            for (int m = 0; m < 4; ++m) {
                const int R = Rb + m;
                const float den = P5f[R] + P5f[64 + R];
                const float inv = 1.0f / (den + 1e-12f);
                og[(size_t)((tt << 6) + R) * 64 + C0] = p0[m] * inv;
                og[(size_t)((tt << 6) + R) * 64 + C1] = p1[m] * inv;
            }
        }
        __syncthreads();
    }
}

extern "C" void kernel_launch(void* const* d_in, const int* in_sizes, int n_in,
                              void* d_out, int out_size, void* d_ws, size_t ws_size,
                              hipStream_t stream) {
    const float* q = (const float*)d_in[0];
    const float* k = (const float*)d_in[1];
    const float* v = (const float*)d_in[2];
    float* out = (float*)d_out;
    float* ws  = (float*)d_ws;
    (void)in_sizes; (void)n_in; (void)out_size; (void)ws_size;

    hipFuncSetAttribute((const void*)k_main,
                        hipFuncAttributeMaxDynamicSharedMemorySize, SMEM_BYTES);

    k_init<<<1, 64, 0, stream>>>(ws);
    k_reduce<<<G_TOT, TPB_R, 0, stream>>>(q, k, ws);
    k_main<<<G_TOT, TPB_M, SMEM_BYTES, stream>>>(q, k, v, ws, out);
}